// Round 4
// baseline (520.529 us; speedup 1.0000x reference)
//
#include <hip/hip_runtime.h>
#include <hip/hip_bf16.h>

#define B_ 4
#define S_ 4096
#define D_ 512
#define SCALE_Q 0.04419417382415922f   // 1/sqrt(512), folded into Q at stage 1

typedef __attribute__((ext_vector_type(8))) short short8;   // 8 x bf16 (4 VGPR) MFMA frag
typedef __attribute__((ext_vector_type(4))) float f32x4;

__device__ __forceinline__ unsigned short f2bf(float f) {
  unsigned u = __builtin_bit_cast(unsigned, f);
  u += 0x7fffu + ((u >> 16) & 1u);          // RNE
  return (unsigned short)(u >> 16);
}

// ---------------------------------------------------------------------------
// Prep: convert Wq/Wk/Wv fp32 [512][512] -> bf16 wb[3][512][512]
// ---------------------------------------------------------------------------
__global__ __launch_bounds__(256) void cvtw_kernel(
    const float* __restrict__ Wq, const float* __restrict__ Wk,
    const float* __restrict__ Wv, unsigned short* __restrict__ wb)
{
  const float* Ws[3] = {Wq, Wk, Wv};
  const int g   = blockIdx.x * 256 + threadIdx.x;  // 0..98303
  const int w   = g >> 15;                         // block-uniform
  const int idx = (g & 32767) * 8;
  const float* src = Ws[w] + idx;
  float4 a = *reinterpret_cast<const float4*>(src);
  float4 b = *reinterpret_cast<const float4*>(src + 4);
  ushort4 h0, h1;
  h0.x = f2bf(a.x); h0.y = f2bf(a.y); h0.z = f2bf(a.z); h0.w = f2bf(a.w);
  h1.x = f2bf(b.x); h1.y = f2bf(b.y); h1.z = f2bf(b.z); h1.w = f2bf(b.w);
  unsigned short* dst = wb + ((size_t)w << 18) + idx;
  *reinterpret_cast<ushort4*>(dst)     = h0;
  *reinterpret_cast<ushort4*>(dst + 4) = h1;
}

// ---------------------------------------------------------------------------
// Stage 1 (512 thr, 8 waves): Q,K,V projections.
//   Q: row-major bf16 [B*S][D], pre-scaled by 1/sqrt(D)
//   K packed per 16-kv tile (kt=s>>4): kp[b][kt][ks][lane][8]
//        elem: s = kt*16 + (lane&15), d = ks*32 + (lane>>4)*8 + j
//   V packed per 16-kv tile: vp[b][kt][cb][lane'(0..31)][8]
//        elem: d = cb*16 + (lane'&15), kv = (lane'>>4)*8 + j   (kv = s&15)
// These linear layouts let attn stage via global_load_lds (lane x 16B) with
// fragments landing exactly where ds_read_b128 wants them.
// ---------------------------------------------------------------------------
__global__ __launch_bounds__(512, 2) void qkv_kernel(
    const float* __restrict__ x,
    const unsigned short* __restrict__ wb,
    const float* __restrict__ bq, const float* __restrict__ bk,
    const float* __restrict__ bv,
    unsigned short* __restrict__ qo, unsigned short* __restrict__ kpk,
    unsigned short* __restrict__ vpk)
{
  __shared__ unsigned short xl[64 * 520];   // 64 rows x 512 (+8 pad) bf16
  __shared__ unsigned short wls[64 * 520];

  const int tid  = threadIdx.x;
  const int lane = tid & 63;
  const int wv   = tid >> 6;      // 0..7
  const int wr   = wv & 3;        // row group (16 rows)
  const int wc   = wv >> 2;       // col half (2 nf each)
  const int m0   = blockIdx.x * 64;
  const int l15  = lane & 15;
  const int lg   = lane >> 4;

  // stage x tile: 8192 float4 / 512 thr = 16 iters
#pragma unroll
  for (int i = 0; i < 16; ++i) {
    int f   = tid + 512 * i;
    int row = f >> 7;
    int c4  = f & 127;
    float4 v = *reinterpret_cast<const float4*>(x + (size_t)(m0 + row) * D_ + c4 * 4);
    ushort4 h;
    h.x = f2bf(v.x); h.y = f2bf(v.y); h.z = f2bf(v.z); h.w = f2bf(v.w);
    *reinterpret_cast<ushort4*>(&xl[row * 520 + c4 * 4]) = h;
  }

  const float* bsel[3] = {bq, bk, bv};

#pragma unroll
  for (int ws = 0; ws < 3; ++ws) {
    for (int nt = 0; nt < 8; ++nt) {
      __syncthreads();
      // stage W n-tile: 4096 uint4 / 512 thr = 8 iters
      const unsigned short* wsrc = wb + ((size_t)ws << 18) + (size_t)nt * 64 * D_;
#pragma unroll
      for (int i = 0; i < 8; ++i) {
        int f   = tid + 512 * i;
        int row = f >> 6;
        int c8  = f & 63;
        uint4 v = *reinterpret_cast<const uint4*>(wsrc + (size_t)row * D_ + c8 * 8);
        *reinterpret_cast<uint4*>(&wls[row * 520 + c8 * 8]) = v;
      }
      __syncthreads();

      f32x4 acc[2];
      acc[0] = f32x4{0.f, 0.f, 0.f, 0.f};
      acc[1] = f32x4{0.f, 0.f, 0.f, 0.f};

      const int arow = wr * 16 + l15;
#pragma unroll
      for (int ks = 0; ks < 16; ++ks) {
        short8 a = *reinterpret_cast<const short8*>(&xl[arow * 520 + ks * 32 + lg * 8]);
#pragma unroll
        for (int c = 0; c < 2; ++c) {
          int nfi = wc * 2 + c;
          short8 bb = *reinterpret_cast<const short8*>(&wls[(nfi * 16 + l15) * 520 + ks * 32 + lg * 8]);
          acc[c] = __builtin_amdgcn_mfma_f32_16x16x32_bf16(a, bb, acc[c], 0, 0, 0);
        }
      }

#pragma unroll
      for (int c = 0; c < 2; ++c) {
        const int col    = nt * 64 + (wc * 2 + c) * 16 + l15;
        const float bias = bsel[ws][col];
        const int rbase  = m0 + wr * 16 + lg * 4;   // C: row=(lane>>4)*4+reg
        const int bbb    = rbase >> 12;
        const int s0     = rbase & 4095;
        if (ws == 2) {
          // packed V
          unsigned short* vdst = vpk + (size_t)bbb * (S_ * D_);
          const int kv0 = s0 & 15;
          size_t off = (size_t)(s0 >> 4) * 8192 + (size_t)(col >> 4) * 256
                     + (size_t)(((kv0 >> 3) << 4) + (col & 15)) * 8 + (kv0 & 7);
          ushort4 h;
          h.x = f2bf(fmaxf(acc[c][0] + bias, 0.f));
          h.y = f2bf(fmaxf(acc[c][1] + bias, 0.f));
          h.z = f2bf(fmaxf(acc[c][2] + bias, 0.f));
          h.w = f2bf(fmaxf(acc[c][3] + bias, 0.f));
          *reinterpret_cast<ushort4*>(vdst + off) = h;
        } else if (ws == 1) {
          // packed K
          unsigned short* kdst = kpk + (size_t)bbb * (S_ * D_);
          size_t off = (size_t)(s0 >> 4) * 8192 + (size_t)(col >> 5) * 512
                     + (size_t)(((((col >> 3) & 3)) << 4) + (s0 & 15)) * 8 + (col & 7);
#pragma unroll
          for (int r = 0; r < 4; ++r)
            kdst[off + r * 8] = f2bf(fmaxf(acc[c][r] + bias, 0.f));
        } else {
          // Q row-major, pre-scaled
#pragma unroll
          for (int r = 0; r < 4; ++r) {
            float v = fmaxf(acc[c][r] + bias, 0.f) * SCALE_Q;
            qo[(size_t)(rbase + r) * D_ + col] = f2bf(v);
          }
        }
      }
    }
  }
}

// ---------------------------------------------------------------------------
// Stage 2: flash attention, 256 blocks x 512 thr (8 waves, 2/SIMD).
// 2 kv-groups (g = wv>>2), each with double-buffered K/V (KVBLK=16, 128KB).
// ALL 8 waves compute every phase:
//   stage_issue(t+1) -> QK(16 q-rows/wave) -> softmax -> write P/fa/flag
//   -> barrier -> n-split PV (each wave: 128 d-cols x all 64 q-rows)
//   -> vmcnt(0) -> barrier.
// PV uses 16x16x32 with P cols 16..31 zero-padded in LDS (0 x finite = 0),
// so V-tile is read ONCE per group (was 4x). Flash-decoding merge at end.
// ---------------------------------------------------------------------------
__global__ __launch_bounds__(512, 2) void attn_kernel(
    const unsigned short* __restrict__ qb_,
    const unsigned short* __restrict__ kp_,
    const unsigned short* __restrict__ vp_,
    float* __restrict__ out)
{
  __shared__ unsigned short kvls[2][2][2][8192];  // [group][buf][K/V][16KB]
  __shared__ unsigned short PLs[2][64][40];       // P: 64 rows x (32 + 8 pad); cols 16..31 = 0
  __shared__ float FAs[2][64];
  __shared__ float MLs[2][64];
  __shared__ float LLs[2][64];
  __shared__ int   FLs[2][4];

  const int tid  = threadIdx.x;
  const int lane = tid & 63;
  const int wv   = tid >> 6;     // 0..7
  const int g    = wv >> 2;      // kv-half group
  const int wl   = wv & 3;       // wave-in-group
  const int l15  = lane & 15;
  const int lg   = lane >> 4;

  const int bid = blockIdx.x;
  const int xcd = bid & 7;
  const int bb  = xcd >> 1;
  const int qt  = (xcd & 1) * 32 + (bid >> 3);

  const unsigned short* qb = qb_ + (size_t)bb * S_ * D_;
  const unsigned short* kp = kp_ + (size_t)bb * (S_ * D_);
  const unsigned short* vp = vp_ + (size_t)bb * (S_ * D_);

  // zero P pad cols 16..31 (written once, never touched again)
  {
    int gz = tid >> 8, row = (tid >> 2) & 63, seg = tid & 3;
    *reinterpret_cast<uint2*>(&PLs[gz][row][16 + seg * 4]) = uint2{0u, 0u};
  }

  const int ktbase = g * 128;          // 16-kv tile index base for this group
  const int q0     = qt * 64 + wl * 16;  // QK-role rows

  auto stage_issue = [&](int kt, int buf) {
    const unsigned short* ksrc = kp + (size_t)kt * 8192;
    const unsigned short* vsrc = vp + (size_t)kt * 8192;
    unsigned short* kl = &kvls[g][buf][0][0];
    unsigned short* vl = &kvls[g][buf][1][0];
#pragma unroll
    for (int ii = 0; ii < 4; ++ii) {
      int i = wl * 4 + ii;
      __builtin_amdgcn_global_load_lds(
          (const __attribute__((address_space(1))) void*)(ksrc + i * 512 + lane * 8),
          (__attribute__((address_space(3))) void*)(kl + i * 512), 16, 0, 0);
      __builtin_amdgcn_global_load_lds(
          (const __attribute__((address_space(1))) void*)(vsrc + i * 512 + lane * 8),
          (__attribute__((address_space(3))) void*)(vl + i * 512), 16, 0, 0);
    }
  };

  // prologue: stage first tile
  stage_issue(ktbase, 0);

  // Q fragments (16 rows x 512 -> 16 frags, 64 VGPR)
  short8 qf[16];
#pragma unroll
  for (int ks = 0; ks < 16; ++ks)
    qf[ks] = *reinterpret_cast<const short8*>(qb + (size_t)(q0 + l15) * D_ + ks * 32 + lg * 8);

  f32x4 o[4][8];
#pragma unroll
  for (int rb = 0; rb < 4; ++rb)
#pragma unroll
    for (int cc = 0; cc < 8; ++cc) o[rb][cc] = f32x4{0.f, 0.f, 0.f, 0.f};
  float m[4], l[4];
#pragma unroll
  for (int r = 0; r < 4; ++r) { m[r] = -1e30f; l[r] = 0.f; }

  asm volatile("s_waitcnt vmcnt(0)" ::: "memory");
  __syncthreads();

  int cur = 0;
  for (int t = 0; t < 128; ++t) {
    if (t + 1 < 128) stage_issue(ktbase + t + 1, cur ^ 1);

    // ---- QK^T: 16 q-rows x 16 kv (scale pre-folded into Q) ----
    const unsigned short* kl = &kvls[g][cur][0][0];
    f32x4 s = f32x4{0.f, 0.f, 0.f, 0.f};
#pragma unroll
    for (int ks = 0; ks < 16; ++ks) {
      short8 kf = *reinterpret_cast<const short8*>(kl + ks * 512 + lane * 8);
      s = __builtin_amdgcn_mfma_f32_16x16x32_bf16(qf[ks], kf, s, 0, 0, 0);
    }

    // ---- online softmax (rows lg*4+r, col l15) ----
    float rmax[4];
#pragma unroll
    for (int r = 0; r < 4; ++r) rmax[r] = s[r];
#pragma unroll
    for (int msk = 1; msk < 16; msk <<= 1) {
#pragma unroll
      for (int r = 0; r < 4; ++r) rmax[r] = fmaxf(rmax[r], __shfl_xor(rmax[r], msk, 64));
    }

    bool grow = (rmax[0] > m[0] + 8.f) || (rmax[1] > m[1] + 8.f) ||
                (rmax[2] > m[2] + 8.f) || (rmax[3] > m[3] + 8.f);
    int flag = __any((int)grow) ? 1 : 0;
    if (flag) {
#pragma unroll
      for (int r = 0; r < 4; ++r) {
        float nm = fmaxf(m[r], rmax[r]);
        float fa = __expf(m[r] - nm);
        m[r] = nm;
        l[r] *= fa;
        if (l15 == 0) FAs[g][wl * 16 + lg * 4 + r] = fa;
      }
    }
    if (lane == 0) FLs[g][wl] = flag;

    f32x4 p;
    float rsum[4];
#pragma unroll
    for (int r = 0; r < 4; ++r) { p[r] = __expf(s[r] - m[r]); rsum[r] = p[r]; }
#pragma unroll
    for (int msk = 1; msk < 16; msk <<= 1) {
#pragma unroll
      for (int r = 0; r < 4; ++r) rsum[r] += __shfl_xor(rsum[r], msk, 64);
    }
#pragma unroll
    for (int r = 0; r < 4; ++r) l[r] += rsum[r];

#pragma unroll
    for (int r = 0; r < 4; ++r)
      PLs[g][wl * 16 + lg * 4 + r][l15] = f2bf(p[r]);

    __syncthreads();   // P / fa / flag visible to whole group

    // ---- PV (n-split): this wave owns d-cols [wl*128, wl*128+128) for ALL 64 rows
    const unsigned short* vl = &kvls[g][cur][1][0];
#pragma unroll
    for (int rb = 0; rb < 4; ++rb) {
      if (FLs[g][rb]) {
        float fr[4];
#pragma unroll
        for (int r = 0; r < 4; ++r) fr[r] = FAs[g][rb * 16 + lg * 4 + r];
#pragma unroll
        for (int cc = 0; cc < 8; ++cc)
#pragma unroll
          for (int r = 0; r < 4; ++r) o[rb][cc][r] *= fr[r];
      }
    }
    short8 pa[4];
#pragma unroll
    for (int rb = 0; rb < 4; ++rb)
      pa[rb] = *reinterpret_cast<const short8*>(&PLs[g][rb * 16 + l15][lg * 8]);
#pragma unroll
    for (int cc = 0; cc < 8; ++cc) {
      int cb = wl * 8 + cc;
      short8 vf = *reinterpret_cast<const short8*>(vl + cb * 256 + (((lg & 1) << 4) + l15) * 8);
#pragma unroll
      for (int rb = 0; rb < 4; ++rb)
        o[rb][cc] = __builtin_amdgcn_mfma_f32_16x16x32_bf16(pa[rb], vf, o[rb][cc], 0, 0, 0);
    }

    asm volatile("s_waitcnt vmcnt(0)" ::: "memory");
    __syncthreads();   // next buffer staged; P region free for overwrite
    cur ^= 1;
  }

  // ---- epilogue: publish per-row m,l ----
  if (l15 == 0) {
#pragma unroll
    for (int r = 0; r < 4; ++r) {
      MLs[g][wl * 16 + lg * 4 + r] = m[r];
      LLs[g][wl * 16 + lg * 4 + r] = l[r];
    }
  }
  __syncthreads();

  float* M = reinterpret_cast<float*>(&kvls[0][0][0][0]);   // 128 KB reuse
  if (g == 1) {
#pragma unroll
    for (int rb = 0; rb < 4; ++rb)
#pragma unroll
      for (int cc = 0; cc < 8; ++cc)
        *reinterpret_cast<f32x4*>(M + wl * 8192 + (rb * 8 + cc) * 256 + lane * 4) = o[rb][cc];
  }
  __syncthreads();
  if (g == 0) {
    float* ob = out + (size_t)bb * S_ * D_;
#pragma unroll
    for (int rb = 0; rb < 4; ++rb) {
      float f0[4], f1[4], inv[4];
#pragma unroll
      for (int r = 0; r < 4; ++r) {
        int row = rb * 16 + lg * 4 + r;
        float m0v = MLs[0][row], m1v = MLs[1][row];
        float l0v = LLs[0][row], l1v = LLs[1][row];
        float mo = fmaxf(m0v, m1v);
        f0[r] = __expf(m0v - mo);
        f1[r] = __expf(m1v - mo);
        inv[r] = 1.0f / (l0v * f0[r] + l1v * f1[r]);
      }
#pragma unroll
      for (int cc = 0; cc < 8; ++cc) {
        f32x4 oB = *reinterpret_cast<const f32x4*>(M + wl * 8192 + (rb * 8 + cc) * 256 + lane * 4);
#pragma unroll
        for (int r = 0; r < 4; ++r) {
          int row = rb * 16 + lg * 4 + r;
          ob[(size_t)(qt * 64 + row) * D_ + wl * 128 + cc * 16 + l15] =
              (o[rb][cc][r] * f0[r] + oB[r] * f1[r]) * inv[r];
        }
      }
    }
  }
}

// ---------------------------------------------------------------------------
extern "C" void kernel_launch(void* const* d_in, const int* in_sizes, int n_in,
                              void* d_out, int out_size, void* d_ws, size_t ws_size,
                              hipStream_t stream) {
  const float* x  = (const float*)d_in[0];
  const float* Wq = (const float*)d_in[1];
  const float* bq = (const float*)d_in[2];
  const float* Wk = (const float*)d_in[3];
  const float* bk = (const float*)d_in[4];
  const float* Wv = (const float*)d_in[5];
  const float* bv = (const float*)d_in[6];
  float* out = (float*)d_out;

  // workspace: Q bf16 | K packed | V packed | Wbf16  (~49.5 MiB)
  unsigned short* q  = (unsigned short*)d_ws;
  unsigned short* kp = q  + (size_t)B_ * S_ * D_;
  unsigned short* vp = kp + (size_t)B_ * S_ * D_;
  unsigned short* wb = vp + (size_t)B_ * S_ * D_;

  cvtw_kernel<<<384, 256, 0, stream>>>(Wq, Wk, Wv, wb);
  qkv_kernel<<<256, 512, 0, stream>>>(x, wb, bq, bk, bv, q, kp, vp);
  attn_kernel<<<256, 512, 0, stream>>>(q, kp, vp, out);
}

// Round 6
// 413.729 us; speedup vs baseline: 1.2581x; 1.2581x over previous
//
#include <hip/hip_runtime.h>
#include <hip/hip_bf16.h>

#define B_ 4
#define S_ 4096
#define D_ 512
#define SCALE_Q 0.04419417382415922f   // 1/sqrt(512), folded into Q at stage 1

typedef __attribute__((ext_vector_type(8))) short short8;   // 8 x bf16 MFMA frag
typedef __attribute__((ext_vector_type(4))) float f32x4;

__device__ __forceinline__ unsigned short f2bf(float f) {
  unsigned u = __builtin_bit_cast(unsigned, f);
  u += 0x7fffu + ((u >> 16) & 1u);          // RNE
  return (unsigned short)(u >> 16);
}

// barrier WITHOUT vmcnt drain: only LDS ops must be ordered (K/V streams are
// register-destined and wave-private). Keeps global prefetches in flight.
__device__ __forceinline__ void lgk_barrier() {
  asm volatile("s_waitcnt lgkmcnt(0)" ::: "memory");
  __builtin_amdgcn_s_barrier();
}

// ---------------------------------------------------------------------------
// Prep: pack Wq/Wk/Wv fp32 -> bf16 FRAG-MAJOR:
//   wfp frag(w, nt, nf, ks) at (((w*8+nt)*4+nf)*16+ks)*512 + (lg*16+l15)*8
//   elem: out-feature col = nt*64+nf*16+l15, d = ks*32+lg*8+j
// ---------------------------------------------------------------------------
__global__ __launch_bounds__(256) void cvtw_kernel(
    const float* __restrict__ Wq, const float* __restrict__ Wk,
    const float* __restrict__ Wv, unsigned short* __restrict__ wfp)
{
  const float* Ws[3] = {Wq, Wk, Wv};
  const int g   = blockIdx.x * 256 + threadIdx.x;  // 0..98303
  const int w   = g >> 15;
  const int off = g & 32767;
  const int row = off >> 6;        // 0..511 (out-feature)
  const int d8  = off & 63;        // 8-elem d chunk
  const float* src = Ws[w] + (size_t)row * D_ + d8 * 8;
  float4 a = *reinterpret_cast<const float4*>(src);
  float4 b = *reinterpret_cast<const float4*>(src + 4);
  ushort4 h0, h1;
  h0.x = f2bf(a.x); h0.y = f2bf(a.y); h0.z = f2bf(a.z); h0.w = f2bf(a.w);
  h1.x = f2bf(b.x); h1.y = f2bf(b.y); h1.z = f2bf(b.z); h1.w = f2bf(b.w);
  const int nt = row >> 6, nf = (row >> 4) & 3, l15r = row & 15;
  const int ks = d8 >> 2, lgv = d8 & 3;
  unsigned short* dst = wfp + ((size_t)(((w * 8 + nt) * 4 + nf) * 16 + ks)) * 512
                      + (lgv * 16 + l15r) * 8;
  *reinterpret_cast<ushort4*>(dst)     = h0;
  *reinterpret_cast<ushort4*>(dst + 4) = h1;
}

// ---------------------------------------------------------------------------
// Stage 1 (512 thr, 8 waves): x in LDS once; W streamed global->reg
// (frag-major, dbl-buffered 8-frag blocks). ZERO barriers in main loop.
//   Q row-major bf16 (pre-scaled); K/V packed frag-major for attn streams:
//   K frag(kt, ct, ks): kv = kt*32+ct*16+l15, d = ks*32+lg*8+j
//   V frag(kt, cb):     d = cb*16+l15,        kv = kt*32+lg*8+j
// ---------------------------------------------------------------------------
__global__ __launch_bounds__(512, 2) void qkv_kernel(
    const float* __restrict__ x,
    const unsigned short* __restrict__ wfp,
    const float* __restrict__ bq, const float* __restrict__ bk,
    const float* __restrict__ bv,
    unsigned short* __restrict__ qo, unsigned short* __restrict__ kpk,
    unsigned short* __restrict__ vpk)
{
  __shared__ unsigned short xl[64 * 520];

  const int tid  = threadIdx.x;
  const int lane = tid & 63;
  const int wv   = tid >> 6;
  const int wr   = wv & 3;        // 16-row group
  const int wc   = wv >> 2;       // 32-col half
  const int m0   = blockIdx.x * 64;
  const int l15  = lane & 15;
  const int lg   = lane >> 4;

  // stage x: 8192 float4 / 512 thr = 16 iters
#pragma unroll
  for (int i = 0; i < 16; ++i) {
    int f   = tid + 512 * i;
    int row = f >> 7;
    int c4  = f & 127;
    float4 v = *reinterpret_cast<const float4*>(x + (size_t)(m0 + row) * D_ + c4 * 4);
    ushort4 h;
    h.x = f2bf(v.x); h.y = f2bf(v.y); h.z = f2bf(v.z); h.w = f2bf(v.w);
    *reinterpret_cast<ushort4*>(&xl[row * 520 + c4 * 4]) = h;
  }
  __syncthreads();

  const float* bsel[3] = {bq, bk, bv};
  const int arow = wr * 16 + l15;

#pragma unroll
  for (int ws = 0; ws < 3; ++ws) {
    for (int nt = 0; nt < 8; ++nt) {
      // this wave's two out-feature frags: nfi = wc*2 + c
      const unsigned short* wbase = wfp + (size_t)(ws * 8 + nt) * 32768
                                  + (size_t)(wc * 2) * 8192 + lane * 8;
      short8 wA[8], wB[8];
      auto LW = [&](short8* dst, int b) {
#pragma unroll
        for (int kk = 0; kk < 4; ++kk)
#pragma unroll
          for (int c = 0; c < 2; ++c)
            dst[kk * 2 + c] = *reinterpret_cast<const short8*>(wbase + c * 8192 + b * 2048 + kk * 512);
      };
      f32x4 aE0{0.f,0.f,0.f,0.f}, aE1{0.f,0.f,0.f,0.f};
      f32x4 aO0{0.f,0.f,0.f,0.f}, aO1{0.f,0.f,0.f,0.f};
      auto MM = [&](const short8* src, int b, f32x4& c0, f32x4& c1) {
#pragma unroll
        for (int kk = 0; kk < 4; ++kk) {
          short8 a = *reinterpret_cast<const short8*>(&xl[arow * 520 + (b * 4 + kk) * 32 + lg * 8]);
          c0 = __builtin_amdgcn_mfma_f32_16x16x32_bf16(a, src[kk * 2 + 0], c0, 0, 0, 0);
          c1 = __builtin_amdgcn_mfma_f32_16x16x32_bf16(a, src[kk * 2 + 1], c1, 0, 0, 0);
        }
      };
      LW(wA, 0);
      LW(wB, 1); MM(wA, 0, aE0, aE1);
      LW(wA, 2); MM(wB, 1, aO0, aO1);
      LW(wB, 3); MM(wA, 2, aE0, aE1);
                 MM(wB, 3, aO0, aO1);
      f32x4 acc[2];
      acc[0] = aE0 + aO0;
      acc[1] = aE1 + aO1;

      // epilogue: bias + relu, packed stores
#pragma unroll
      for (int c = 0; c < 2; ++c) {
        const int col    = nt * 64 + (wc * 2 + c) * 16 + l15;
        const float bias = bsel[ws][col];
        const int rbase  = m0 + wr * 16 + lg * 4;   // C: row=(lane>>4)*4+reg
        const int bbb    = rbase >> 12;
        const int s0     = rbase & 4095;
        if (ws == 2) {
          // V frag-major: kt*16384 + cb*512 + (lgv*16+l15v)*8 + j
          unsigned short* vdst = vpk + (size_t)bbb * (S_ * D_);
          size_t off = (size_t)(s0 >> 5) * 16384 + (size_t)(col >> 4) * 512
                     + (size_t)(((s0 >> 3) & 3) * 16 + (col & 15)) * 8 + (s0 & 7);
          ushort4 h;
          h.x = f2bf(fmaxf(acc[c][0] + bias, 0.f));
          h.y = f2bf(fmaxf(acc[c][1] + bias, 0.f));
          h.z = f2bf(fmaxf(acc[c][2] + bias, 0.f));
          h.w = f2bf(fmaxf(acc[c][3] + bias, 0.f));
          *reinterpret_cast<ushort4*>(vdst + off) = h;
        } else if (ws == 1) {
          // K frag-major: kt*16384 + (ct*16+ks)*512 + (lgk*16+kvpos)*8 + j
          unsigned short* kdst = kpk + (size_t)bbb * (S_ * D_);
          size_t off = (size_t)(s0 >> 5) * 16384
                     + (size_t)(((s0 >> 4) & 1) * 16 + (col >> 5)) * 512
                     + (size_t)(((col >> 3) & 3) * 16 + (s0 & 15)) * 8 + (col & 7);
#pragma unroll
          for (int r = 0; r < 4; ++r)
            kdst[off + r * 8] = f2bf(fmaxf(acc[c][r] + bias, 0.f));
        } else {
          // Q row-major, pre-scaled
#pragma unroll
          for (int r = 0; r < 4; ++r) {
            float v = fmaxf(acc[c][r] + bias, 0.f) * SCALE_Q;
            qo[(size_t)(rbase + r) * D_ + col] = f2bf(v);
          }
        }
      }
    }
  }
}

// ---------------------------------------------------------------------------
// Stage 2: flash attention, 256 blocks x 512 thr, producer-consumer.
// Waves 0-3 (QK): 16 q-rows each, KVBLK=32, K streamed global->reg,
//   swapped mfma(K,Q) -> S^T so softmax is lane-local (q = l15);
//   defer-max; P/fa/flag handed to PV via small LDS dbuf.
// Waves 4-7 (PV): n-split 128 d-cols x all 64 q-rows, K=32 unpadded,
//   V streamed global->reg (frags reused 4x), O in 128 VGPR.
// ONE lgk-barrier per iter (no vmcnt drain -> prefetches fly across it).
// Separate role loops with matched barrier counts (regalloc friendly).
// ---------------------------------------------------------------------------
__global__ __launch_bounds__(512, 2) void attn_kernel(
    const unsigned short* __restrict__ qb_,
    const unsigned short* __restrict__ kp_,
    const unsigned short* __restrict__ vp_,
    float* __restrict__ out)
{
  __shared__ unsigned short pl[2][64][48];   // P: [parity][q][kv 0..31] (+16 pad)
  __shared__ float FAs[2][64];
  __shared__ int   FLs[2][4];
  __shared__ float Linv[64];

  const int tid  = threadIdx.x;
  const int lane = tid & 63;
  const int wv   = tid >> 6;
  const int wid  = wv & 3;
  const int l15  = lane & 15;
  const int lg   = lane >> 4;

  const int bid = blockIdx.x;
  const int xcd = bid & 7;
  const int bb  = xcd >> 1;
  const int qt  = (xcd & 1) * 32 + (bid >> 3);

  const unsigned short* qb  = qb_ + (size_t)bb * S_ * D_;
  const unsigned short* kpB = kp_ + (size_t)bb * (S_ * D_);
  const unsigned short* vpB = vp_ + (size_t)bb * (S_ * D_);

  if (wv < 4) {
    // ================= QK role =================
    const int q0 = qt * 64 + wid * 16;
    short8 qf[16];
#pragma unroll
    for (int ks = 0; ks < 16; ++ks)
      qf[ks] = *reinterpret_cast<const short8*>(qb + (size_t)(q0 + l15) * D_ + ks * 32 + lg * 8);

    short8 ka[8], kb[8];
    auto LK = [&](short8* dst, const unsigned short* base, int b) {
#pragma unroll
      for (int kk = 0; kk < 4; ++kk)
#pragma unroll
        for (int ct = 0; ct < 2; ++ct)
          dst[kk * 2 + ct] = *reinterpret_cast<const short8*>(base + ct * 8192 + b * 2048 + kk * 512 + lane * 8);
    };
    LK(ka, kpB, 0);   // tile 0, block 0

    float mrun = -1e30f, lrun = 0.f;

    for (int t = 0; t < 129; ++t) {
      lgk_barrier();
      if (t < 128) {
        const unsigned short* kt_base  = kpB + (size_t)t * 16384;
        const unsigned short* ktn_base = kpB + (size_t)((t + 1) & 127) * 16384;
        f32x4 sE0{0.f,0.f,0.f,0.f}, sE1{0.f,0.f,0.f,0.f};
        f32x4 sO0{0.f,0.f,0.f,0.f}, sO1{0.f,0.f,0.f,0.f};
        auto MK = [&](const short8* src, int b, f32x4& c0, f32x4& c1) {
#pragma unroll
          for (int kk = 0; kk < 4; ++kk) {
            short8 q = qf[b * 4 + kk];
            c0 = __builtin_amdgcn_mfma_f32_16x16x32_bf16(src[kk * 2 + 0], q, c0, 0, 0, 0);
            c1 = __builtin_amdgcn_mfma_f32_16x16x32_bf16(src[kk * 2 + 1], q, c1, 0, 0, 0);
          }
        };
        LK(kb, kt_base, 1);  MK(ka, 0, sE0, sE1);
        LK(ka, kt_base, 2);  MK(kb, 1, sO0, sO1);
        LK(kb, kt_base, 3);  MK(ka, 2, sE0, sE1);
        LK(ka, ktn_base, 0); MK(kb, 3, sO0, sO1);
        f32x4 s0 = sE0 + sO0;   // kv = 0*16 + lg*4 + r, q = l15
        f32x4 s1 = sE1 + sO1;   // kv = 1*16 + lg*4 + r

        // lane-local softmax stats (q = l15; reduce over lg via 2 shfls)
        float rmax = fmaxf(fmaxf(fmaxf(s0[0], s0[1]), fmaxf(s0[2], s0[3])),
                           fmaxf(fmaxf(s1[0], s1[1]), fmaxf(s1[2], s1[3])));
        rmax = fmaxf(rmax, __shfl_xor(rmax, 16, 64));
        rmax = fmaxf(rmax, __shfl_xor(rmax, 32, 64));

        const int par = t & 1;
        int flag = __any((int)(rmax > mrun + 8.f));
        if (flag) {
          float nm = fmaxf(mrun, rmax);
          float fa = __expf(mrun - nm);
          mrun = nm;
          lrun *= fa;
          if (lane < 16) FAs[par][wid * 16 + lane] = fa;
        }
        if (lane == 0) FLs[par][wid] = flag ? 1 : 0;

        f32x4 p0, p1;
#pragma unroll
        for (int r = 0; r < 4; ++r) {
          p0[r] = __expf(s0[r] - mrun);
          p1[r] = __expf(s1[r] - mrun);
        }
        float rs = (p0[0] + p0[1]) + (p0[2] + p0[3]) + (p1[0] + p1[1]) + (p1[2] + p1[3]);
        rs += __shfl_xor(rs, 16, 64);
        rs += __shfl_xor(rs, 32, 64);
        lrun += rs;

        // P -> LDS handoff, row = wid*16+l15, packed u32 pairs
        unsigned short* prow = &pl[par][wid * 16 + l15][0];
        unsigned q00 = (unsigned)f2bf(p0[0]) | ((unsigned)f2bf(p0[1]) << 16);
        unsigned q01 = (unsigned)f2bf(p0[2]) | ((unsigned)f2bf(p0[3]) << 16);
        unsigned q10 = (unsigned)f2bf(p1[0]) | ((unsigned)f2bf(p1[1]) << 16);
        unsigned q11 = (unsigned)f2bf(p1[2]) | ((unsigned)f2bf(p1[3]) << 16);
        *reinterpret_cast<unsigned*>(prow + lg * 4)          = q00;
        *reinterpret_cast<unsigned*>(prow + lg * 4 + 2)      = q01;
        *reinterpret_cast<unsigned*>(prow + 16 + lg * 4)     = q10;
        *reinterpret_cast<unsigned*>(prow + 16 + lg * 4 + 2) = q11;
      }
    }
    if (lane < 16) Linv[wid * 16 + lane] = 1.0f / lrun;
    lgk_barrier();
  } else {
    // ================= PV role =================
    f32x4 o[4][8];
#pragma unroll
    for (int rb = 0; rb < 4; ++rb)
#pragma unroll
      for (int cc = 0; cc < 8; ++cc) o[rb][cc] = f32x4{0.f, 0.f, 0.f, 0.f};

    short8 vf[8];
#pragma unroll
    for (int cc = 0; cc < 8; ++cc)
      vf[cc] = *reinterpret_cast<const short8*>(vpB + (size_t)(wid * 8 + cc) * 512 + lane * 8);

    for (int t = 0; t < 129; ++t) {
      lgk_barrier();
      if (t >= 1) {
        const int j = t - 1, par = j & 1;
        // deferred rescale (wave-uniform flag per row-group)
#pragma unroll
        for (int rb = 0; rb < 4; ++rb) {
          if (FLs[par][rb]) {
            f32x4 fa4 = *reinterpret_cast<const f32x4*>(&FAs[par][rb * 16 + lg * 4]);
#pragma unroll
            for (int cc = 0; cc < 8; ++cc)
#pragma unroll
              for (int r = 0; r < 4; ++r) o[rb][cc][r] *= fa4[r];
          }
        }
        short8 pa[4];
#pragma unroll
        for (int rb = 0; rb < 4; ++rb)
          pa[rb] = *reinterpret_cast<const short8*>(&pl[par][rb * 16 + l15][lg * 8]);
#pragma unroll
        for (int cc = 0; cc < 8; ++cc) {
          short8 vv = vf[cc];
#pragma unroll
          for (int rb = 0; rb < 4; ++rb)
            o[rb][cc] = __builtin_amdgcn_mfma_f32_16x16x32_bf16(pa[rb], vv, o[rb][cc], 0, 0, 0);
        }
        if (j + 1 < 128) {
#pragma unroll
          for (int cc = 0; cc < 8; ++cc)
            vf[cc] = *reinterpret_cast<const short8*>(
                vpB + (size_t)(j + 1) * 16384 + (size_t)(wid * 8 + cc) * 512 + lane * 8);
        }
      }
    }
    lgk_barrier();

    // epilogue: normalize + store (O rows q = rb*16+lg*4+r, cols wid*128+cc*16+l15)
    float* ob = out + (size_t)bb * S_ * D_ + (size_t)qt * 64 * D_ + wid * 128;
#pragma unroll
    for (int rb = 0; rb < 4; ++rb) {
      f32x4 linv = *reinterpret_cast<const f32x4*>(&Linv[rb * 16 + lg * 4]);
#pragma unroll
      for (int cc = 0; cc < 8; ++cc)
#pragma unroll
        for (int r = 0; r < 4; ++r)
          ob[(size_t)(rb * 16 + lg * 4 + r) * D_ + cc * 16 + l15] = o[rb][cc][r] * linv[r];
    }
  }
}

// ---------------------------------------------------------------------------
extern "C" void kernel_launch(void* const* d_in, const int* in_sizes, int n_in,
                              void* d_out, int out_size, void* d_ws, size_t ws_size,
                              hipStream_t stream) {
  const float* x  = (const float*)d_in[0];
  const float* Wq = (const float*)d_in[1];
  const float* bq = (const float*)d_in[2];
  const float* Wk = (const float*)d_in[3];
  const float* bk = (const float*)d_in[4];
  const float* Wv = (const float*)d_in[5];
  const float* bv = (const float*)d_in[6];
  float* out = (float*)d_out;

  // workspace: Q bf16 | K frag-packed | V frag-packed | W frag-packed (~49.5 MiB)
  unsigned short* q   = (unsigned short*)d_ws;
  unsigned short* kp  = q  + (size_t)B_ * S_ * D_;
  unsigned short* vp  = kp + (size_t)B_ * S_ * D_;
  unsigned short* wfp = vp + (size_t)B_ * S_ * D_;

  cvtw_kernel<<<384, 256, 0, stream>>>(Wq, Wk, Wv, wfp);
  qkv_kernel<<<256, 512, 0, stream>>>(x, wfp, bq, bk, bv, q, kp, vp);
  attn_kernel<<<256, 512, 0, stream>>>(q, kp, vp, out);
}

// Round 7
// 285.632 us; speedup vs baseline: 1.8224x; 1.4485x over previous
//
#include <hip/hip_runtime.h>
#include <hip/hip_bf16.h>

#define B_ 4
#define S_ 4096
#define D_ 512
#define SCALE_Q 0.04419417382415922f   // 1/sqrt(512), folded into Q at stage 1

typedef __attribute__((ext_vector_type(8))) short short8;   // 8 x bf16 MFMA frag
typedef __attribute__((ext_vector_type(4))) float f32x4;

__device__ __forceinline__ unsigned short f2bf(float f) {
  unsigned u = __builtin_bit_cast(unsigned, f);
  u += 0x7fffu + ((u >> 16) & 1u);          // RNE
  return (unsigned short)(u >> 16);
}

// ---------------------------------------------------------------------------
// Prep: pack Wq/Wk/Wv fp32 -> bf16 FRAG-MAJOR:
//   wfp frag(w, nt, nf, ks) at (((w*8+nt)*4+nf)*16+ks)*512 + (lg*16+l15)*8
//   elem: out-feature col = nt*64+nf*16+l15, d = ks*32+lg*8+j
// ---------------------------------------------------------------------------
__global__ __launch_bounds__(256) void cvtw_kernel(
    const float* __restrict__ Wq, const float* __restrict__ Wk,
    const float* __restrict__ Wv, unsigned short* __restrict__ wfp)
{
  const float* Ws[3] = {Wq, Wk, Wv};
  const int g   = blockIdx.x * 256 + threadIdx.x;  // 0..98303
  const int w   = g >> 15;
  const int off = g & 32767;
  const int row = off >> 6;        // 0..511 (out-feature)
  const int d8  = off & 63;        // 8-elem d chunk
  const float* src = Ws[w] + (size_t)row * D_ + d8 * 8;
  float4 a = *reinterpret_cast<const float4*>(src);
  float4 b = *reinterpret_cast<const float4*>(src + 4);
  ushort4 h0, h1;
  h0.x = f2bf(a.x); h0.y = f2bf(a.y); h0.z = f2bf(a.z); h0.w = f2bf(a.w);
  h1.x = f2bf(b.x); h1.y = f2bf(b.y); h1.z = f2bf(b.z); h1.w = f2bf(b.w);
  const int nt = row >> 6, nf = (row >> 4) & 3, l15r = row & 15;
  const int ks = d8 >> 2, lgv = d8 & 3;
  unsigned short* dst = wfp + ((size_t)(((w * 8 + nt) * 4 + nf) * 16 + ks)) * 512
                      + (lgv * 16 + l15r) * 8;
  *reinterpret_cast<ushort4*>(dst)     = h0;
  *reinterpret_cast<ushort4*>(dst + 4) = h1;
}

// ---------------------------------------------------------------------------
// Stage 1 (512 thr, 8 waves): x in LDS once; wave wv owns output cols
// [wv*64, wv*64+64) (nt = wv, all 4 nf) -> ZERO W duplication across waves;
// W frags streamed global->reg (dbuf 8-frag chunks), each reused 4x across
// row-groups. K computed with SWAPPED mfma(W, x) so packed K stores are
// vectorized ushort4. Zero barriers in the main loop.
//   Q row-major bf16 (pre-scaled); packed layouts for attn:
//   K frag(kt, ct, ks): kv = kt*32+ct*16+l15, d = ks*32+lg*8+j
//   V frag(kt, cb):     d = cb*16+l15,        kv = kt*32+lg*8+j
// ---------------------------------------------------------------------------
__global__ __launch_bounds__(512, 2) void qkv_kernel(
    const float* __restrict__ x,
    const unsigned short* __restrict__ wfp,
    const float* __restrict__ bq, const float* __restrict__ bk,
    const float* __restrict__ bv,
    unsigned short* __restrict__ qo, unsigned short* __restrict__ kpk,
    unsigned short* __restrict__ vpk)
{
  __shared__ unsigned short xl[64 * 520];

  const int tid  = threadIdx.x;
  const int lane = tid & 63;
  const int wv   = tid >> 6;      // 0..7 -> owns cols [wv*64, wv*64+64)
  const int m0   = blockIdx.x * 64;
  const int l15  = lane & 15;
  const int lg   = lane >> 4;

  // stage x: 8192 float4 / 512 thr = 16 iters
#pragma unroll
  for (int i = 0; i < 16; ++i) {
    int f   = tid + 512 * i;
    int row = f >> 7;
    int c4  = f & 127;
    float4 v = *reinterpret_cast<const float4*>(x + (size_t)(m0 + row) * D_ + c4 * 4);
    ushort4 h;
    h.x = f2bf(v.x); h.y = f2bf(v.y); h.z = f2bf(v.z); h.w = f2bf(v.w);
    *reinterpret_cast<ushort4*>(&xl[row * 520 + c4 * 4]) = h;
  }
  __syncthreads();

#pragma unroll
  for (int ws = 0; ws < 3; ++ws) {
    // frag(ws, nt=wv, nf, ks) at (ws*8+wv)*32768 + (nf*16+ks)*512 shorts
    const unsigned short* wbase = wfp + (size_t)(ws * 8 + wv) * 32768 + lane * 8;
    short8 wA[8], wB[8];
    auto LW = [&](short8* d, int kp) {           // load 4 nf x 2 ks frags
#pragma unroll
      for (int nf = 0; nf < 4; ++nf)
#pragma unroll
        for (int kk = 0; kk < 2; ++kk)
          d[nf * 2 + kk] = *reinterpret_cast<const short8*>(
              wbase + (size_t)(nf * 16 + kp * 2 + kk) * 512);
    };

    f32x4 acc[4][4];                             // [row-group][nf]
#pragma unroll
    for (int rg = 0; rg < 4; ++rg)
#pragma unroll
      for (int nf = 0; nf < 4; ++nf) acc[rg][nf] = f32x4{0.f, 0.f, 0.f, 0.f};

    auto DO = [&](const short8* w, int kp) {     // 8 ds_read + 32 MFMA
      __builtin_amdgcn_s_setprio(1);
#pragma unroll
      for (int rg = 0; rg < 4; ++rg) {
        short8 a0 = *reinterpret_cast<const short8*>(
            &xl[(rg * 16 + l15) * 520 + (kp * 2) * 32 + lg * 8]);
        short8 a1 = *reinterpret_cast<const short8*>(
            &xl[(rg * 16 + l15) * 520 + (kp * 2 + 1) * 32 + lg * 8]);
#pragma unroll
        for (int nf = 0; nf < 4; ++nf) {
          if (ws == 1) {   // swapped: C rows = d (features), cols = tokens
            acc[rg][nf] = __builtin_amdgcn_mfma_f32_16x16x32_bf16(w[nf * 2 + 0], a0, acc[rg][nf], 0, 0, 0);
            acc[rg][nf] = __builtin_amdgcn_mfma_f32_16x16x32_bf16(w[nf * 2 + 1], a1, acc[rg][nf], 0, 0, 0);
          } else {
            acc[rg][nf] = __builtin_amdgcn_mfma_f32_16x16x32_bf16(a0, w[nf * 2 + 0], acc[rg][nf], 0, 0, 0);
            acc[rg][nf] = __builtin_amdgcn_mfma_f32_16x16x32_bf16(a1, w[nf * 2 + 1], acc[rg][nf], 0, 0, 0);
          }
        }
      }
      __builtin_amdgcn_s_setprio(0);
    };

    LW(wA, 0);
    LW(wB, 1); DO(wA, 0);
    LW(wA, 2); DO(wB, 1);
    LW(wB, 3); DO(wA, 2);
    LW(wA, 4); DO(wB, 3);
    LW(wB, 5); DO(wA, 4);
    LW(wA, 6); DO(wB, 5);
    LW(wB, 7); DO(wA, 6);
               DO(wB, 7);

    // ---- epilogue ----
    if (ws == 0) {
#pragma unroll
      for (int nf = 0; nf < 4; ++nf) {
        const int col   = wv * 64 + nf * 16 + l15;
        const float bias = bq[col];
#pragma unroll
        for (int rg = 0; rg < 4; ++rg) {
          const int rbase = m0 + rg * 16 + lg * 4;
#pragma unroll
          for (int r = 0; r < 4; ++r)
            qo[(size_t)(rbase + r) * D_ + col] =
                f2bf(fmaxf(acc[rg][nf][r] + bias, 0.f) * SCALE_Q);
        }
      }
    } else if (ws == 1) {
      // swapped C: row = d-local (lg*4+r), col = token (l15)
#pragma unroll
      for (int nf = 0; nf < 4; ++nf) {
        const int d0 = wv * 64 + nf * 16 + lg * 4;
        float4 b4 = *reinterpret_cast<const float4*>(bk + d0);
#pragma unroll
        for (int rg = 0; rg < 4; ++rg) {
          const int srow = m0 + rg * 16 + l15;
          const int bbb  = srow >> 12;
          const int s0   = srow & 4095;
          unsigned short* kdst = kpk + (size_t)bbb * (S_ * D_);
          size_t off = (size_t)(s0 >> 5) * 16384
                     + (size_t)(((s0 >> 4) & 1) * 16 + (d0 >> 5)) * 512
                     + (size_t)(((d0 >> 3) & 3) * 16 + (s0 & 15)) * 8 + (d0 & 7);
          ushort4 h;
          h.x = f2bf(fmaxf(acc[rg][nf][0] + b4.x, 0.f));
          h.y = f2bf(fmaxf(acc[rg][nf][1] + b4.y, 0.f));
          h.z = f2bf(fmaxf(acc[rg][nf][2] + b4.z, 0.f));
          h.w = f2bf(fmaxf(acc[rg][nf][3] + b4.w, 0.f));
          *reinterpret_cast<ushort4*>(kdst + off) = h;
        }
      }
    } else {
#pragma unroll
      for (int nf = 0; nf < 4; ++nf) {
        const int col   = wv * 64 + nf * 16 + l15;
        const float bias = bv[col];
#pragma unroll
        for (int rg = 0; rg < 4; ++rg) {
          const int rbase = m0 + rg * 16 + lg * 4;
          const int bbb   = rbase >> 12;
          const int s0    = rbase & 4095;
          unsigned short* vdst = vpk + (size_t)bbb * (S_ * D_);
          size_t off = (size_t)(s0 >> 5) * 16384 + (size_t)(col >> 4) * 512
                     + (size_t)(((s0 >> 3) & 3) * 16 + (col & 15)) * 8 + (s0 & 7);
          ushort4 h;
          h.x = f2bf(fmaxf(acc[rg][nf][0] + bias, 0.f));
          h.y = f2bf(fmaxf(acc[rg][nf][1] + bias, 0.f));
          h.z = f2bf(fmaxf(acc[rg][nf][2] + bias, 0.f));
          h.w = f2bf(fmaxf(acc[rg][nf][3] + bias, 0.f));
          *reinterpret_cast<ushort4*>(vdst + off) = h;
        }
      }
    }
  }
}

// ---------------------------------------------------------------------------
// Stage 2: flash attention, 256 blocks x 512 thr, producer-consumer.
// Waves 0-3 (QK): K tile staged ONCE per iter into LDS dbuf via
//   global_load_lds (frag-linear, conflict-free), shared by all 4 QK waves
//   (kills the 4x L2 duplication). QK's only vmem = 8 stage loads/iter ->
//   vmcnt(0) at its barrier is free. Swapped mfma(K,Q), lane-local softmax,
//   defer-max; P handed to PV via small LDS dbuf.
// Waves 4-7 (PV): V streamed global->reg (disjoint n-split), lgkmcnt-only
//   barriers so V prefetches stay in flight across barriers.
// ---------------------------------------------------------------------------
__global__ __launch_bounds__(512, 2) void attn_kernel(
    const unsigned short* __restrict__ qb_,
    const unsigned short* __restrict__ kp_,
    const unsigned short* __restrict__ vp_,
    float* __restrict__ out)
{
  __shared__ unsigned short kls[2][16384];   // K dbuf: 2 x 32 KB, frag-linear
  __shared__ unsigned short pl[2][64][48];   // P: [parity][q][kv 0..31] (+16 pad)
  __shared__ float FAs[2][64];
  __shared__ int   FLs[2][4];
  __shared__ float Linv[64];

  const int tid  = threadIdx.x;
  const int lane = tid & 63;
  const int wv   = tid >> 6;
  const int wid  = wv & 3;
  const int l15  = lane & 15;
  const int lg   = lane >> 4;

  const int bid = blockIdx.x;
  const int xcd = bid & 7;
  const int bb  = xcd >> 1;
  const int qt  = (xcd & 1) * 32 + (bid >> 3);

  const unsigned short* qb  = qb_ + (size_t)bb * S_ * D_;
  const unsigned short* kpB = kp_ + (size_t)bb * (S_ * D_);
  const unsigned short* vpB = vp_ + (size_t)bb * (S_ * D_);

  if (wv < 4) {
    // ================= QK role =================
    const int q0 = qt * 64 + wid * 16;
    short8 qf[16];
#pragma unroll
    for (int ks = 0; ks < 16; ++ks)
      qf[ks] = *reinterpret_cast<const short8*>(qb + (size_t)(q0 + l15) * D_ + ks * 32 + lg * 8);

    auto stageK = [&](int kt, int buf) {   // 4 QK waves cover 32 KB (8 instr each)
      const unsigned short* ksrc = kpB + (size_t)kt * 16384;
#pragma unroll
      for (int ii = 0; ii < 8; ++ii) {
        int i = wid * 8 + ii;
        __builtin_amdgcn_global_load_lds(
            (const __attribute__((address_space(1))) void*)(ksrc + i * 512 + lane * 8),
            (__attribute__((address_space(3))) void*)(&kls[buf][i * 512]), 16, 0, 0);
      }
    };
    auto RD = [&](short8* dst, int cur, int b) {
#pragma unroll
      for (int kk = 0; kk < 4; ++kk)
#pragma unroll
        for (int ct = 0; ct < 2; ++ct)
          dst[kk * 2 + ct] = *reinterpret_cast<const short8*>(
              &kls[cur][(ct * 16 + b * 4 + kk) * 512 + lane * 8]);
    };

    stageK(0, 0);
    float mrun = -1e30f, lrun = 0.f;
    short8 ka[8], kb[8];

    for (int t = 0; t < 129; ++t) {
      // barrier with vmcnt(0): drains stage(t) (issued a full iter ago -> free)
      asm volatile("s_waitcnt vmcnt(0) lgkmcnt(0)" ::: "memory");
      __builtin_amdgcn_s_barrier();
      if (t < 128) {
        const int cur = t & 1;
        if (t + 1 < 128) stageK(t + 1, cur ^ 1);

        f32x4 sE0{0.f,0.f,0.f,0.f}, sE1{0.f,0.f,0.f,0.f};
        f32x4 sO0{0.f,0.f,0.f,0.f}, sO1{0.f,0.f,0.f,0.f};
        auto MK = [&](const short8* src, int b, f32x4& c0, f32x4& c1) {
          __builtin_amdgcn_s_setprio(1);
#pragma unroll
          for (int kk = 0; kk < 4; ++kk) {
            short8 q = qf[b * 4 + kk];
            c0 = __builtin_amdgcn_mfma_f32_16x16x32_bf16(src[kk * 2 + 0], q, c0, 0, 0, 0);
            c1 = __builtin_amdgcn_mfma_f32_16x16x32_bf16(src[kk * 2 + 1], q, c1, 0, 0, 0);
          }
          __builtin_amdgcn_s_setprio(0);
        };
        RD(ka, cur, 0);
        RD(kb, cur, 1); MK(ka, 0, sE0, sE1);
        RD(ka, cur, 2); MK(kb, 1, sO0, sO1);
        RD(kb, cur, 3); MK(ka, 2, sE0, sE1);
                        MK(kb, 3, sO0, sO1);
        f32x4 s0 = sE0 + sO0;   // kv = lg*4+r,      q = l15
        f32x4 s1 = sE1 + sO1;   // kv = 16+lg*4+r,   q = l15

        float rmax = fmaxf(fmaxf(fmaxf(s0[0], s0[1]), fmaxf(s0[2], s0[3])),
                           fmaxf(fmaxf(s1[0], s1[1]), fmaxf(s1[2], s1[3])));
        rmax = fmaxf(rmax, __shfl_xor(rmax, 16, 64));
        rmax = fmaxf(rmax, __shfl_xor(rmax, 32, 64));

        const int par = t & 1;
        int flag = __any((int)(rmax > mrun + 8.f));
        if (flag) {
          float nm = fmaxf(mrun, rmax);
          float fa = __expf(mrun - nm);
          mrun = nm;
          lrun *= fa;
          if (lane < 16) FAs[par][wid * 16 + lane] = fa;
        }
        if (lane == 0) FLs[par][wid] = flag ? 1 : 0;

        f32x4 p0, p1;
#pragma unroll
        for (int r = 0; r < 4; ++r) {
          p0[r] = __expf(s0[r] - mrun);
          p1[r] = __expf(s1[r] - mrun);
        }
        float rs = (p0[0] + p0[1]) + (p0[2] + p0[3]) + (p1[0] + p1[1]) + (p1[2] + p1[3]);
        rs += __shfl_xor(rs, 16, 64);
        rs += __shfl_xor(rs, 32, 64);
        lrun += rs;

        unsigned short* prow = &pl[par][wid * 16 + l15][0];
        unsigned q00 = (unsigned)f2bf(p0[0]) | ((unsigned)f2bf(p0[1]) << 16);
        unsigned q01 = (unsigned)f2bf(p0[2]) | ((unsigned)f2bf(p0[3]) << 16);
        unsigned q10 = (unsigned)f2bf(p1[0]) | ((unsigned)f2bf(p1[1]) << 16);
        unsigned q11 = (unsigned)f2bf(p1[2]) | ((unsigned)f2bf(p1[3]) << 16);
        *reinterpret_cast<unsigned*>(prow + lg * 4)          = q00;
        *reinterpret_cast<unsigned*>(prow + lg * 4 + 2)      = q01;
        *reinterpret_cast<unsigned*>(prow + 16 + lg * 4)     = q10;
        *reinterpret_cast<unsigned*>(prow + 16 + lg * 4 + 2) = q11;
      }
    }
    if (lane < 16) Linv[wid * 16 + lane] = 1.0f / lrun;
    asm volatile("s_waitcnt vmcnt(0) lgkmcnt(0)" ::: "memory");
    __builtin_amdgcn_s_barrier();
  } else {
    // ================= PV role =================
    f32x4 o[4][8];
#pragma unroll
    for (int rb = 0; rb < 4; ++rb)
#pragma unroll
      for (int cc = 0; cc < 8; ++cc) o[rb][cc] = f32x4{0.f, 0.f, 0.f, 0.f};

    short8 vf[8];
#pragma unroll
    for (int cc = 0; cc < 8; ++cc)
      vf[cc] = *reinterpret_cast<const short8*>(vpB + (size_t)(wid * 8 + cc) * 512 + lane * 8);

    for (int t = 0; t < 129; ++t) {
      asm volatile("s_waitcnt lgkmcnt(0)" ::: "memory");
      __builtin_amdgcn_s_barrier();
      if (t >= 1) {
        const int j = t - 1, par = j & 1;
#pragma unroll
        for (int rb = 0; rb < 4; ++rb) {
          if (FLs[par][rb]) {
            f32x4 fa4 = *reinterpret_cast<const f32x4*>(&FAs[par][rb * 16 + lg * 4]);
#pragma unroll
            for (int cc = 0; cc < 8; ++cc)
#pragma unroll
              for (int r = 0; r < 4; ++r) o[rb][cc][r] *= fa4[r];
          }
        }
        short8 pa[4];
#pragma unroll
        for (int rb = 0; rb < 4; ++rb)
          pa[rb] = *reinterpret_cast<const short8*>(&pl[par][rb * 16 + l15][lg * 8]);
        __builtin_amdgcn_s_setprio(1);
#pragma unroll
        for (int cc = 0; cc < 8; ++cc) {
          short8 vv = vf[cc];
#pragma unroll
          for (int rb = 0; rb < 4; ++rb)
            o[rb][cc] = __builtin_amdgcn_mfma_f32_16x16x32_bf16(pa[rb], vv, o[rb][cc], 0, 0, 0);
        }
        __builtin_amdgcn_s_setprio(0);
        if (j + 1 < 128) {
#pragma unroll
          for (int cc = 0; cc < 8; ++cc)
            vf[cc] = *reinterpret_cast<const short8*>(
                vpB + (size_t)(j + 1) * 16384 + (size_t)(wid * 8 + cc) * 512 + lane * 8);
        }
      }
    }
    asm volatile("s_waitcnt lgkmcnt(0)" ::: "memory");
    __builtin_amdgcn_s_barrier();

    // epilogue: normalize + store (rows q = rb*16+lg*4+r, cols wid*128+cc*16+l15)
    float* ob = out + (size_t)bb * S_ * D_ + (size_t)qt * 64 * D_ + wid * 128;
#pragma unroll
    for (int rb = 0; rb < 4; ++rb) {
      f32x4 linv = *reinterpret_cast<const f32x4*>(&Linv[rb * 16 + lg * 4]);
#pragma unroll
      for (int cc = 0; cc < 8; ++cc)
#pragma unroll
        for (int r = 0; r < 4; ++r)
          ob[(size_t)(rb * 16 + lg * 4 + r) * D_ + cc * 16 + l15] = o[rb][cc][r] * linv[r];
    }
  }
}

// ---------------------------------------------------------------------------
extern "C" void kernel_launch(void* const* d_in, const int* in_sizes, int n_in,
                              void* d_out, int out_size, void* d_ws, size_t ws_size,
                              hipStream_t stream) {
  const float* x  = (const float*)d_in[0];
  const float* Wq = (const float*)d_in[1];
  const float* bq = (const float*)d_in[2];
  const float* Wk = (const float*)d_in[3];
  const float* bk = (const float*)d_in[4];
  const float* Wv = (const float*)d_in[5];
  const float* bv = (const float*)d_in[6];
  float* out = (float*)d_out;

  // workspace: Q bf16 | K frag-packed | V frag-packed | W frag-packed (~49.5 MiB)
  unsigned short* q   = (unsigned short*)d_ws;
  unsigned short* kp  = q  + (size_t)B_ * S_ * D_;
  unsigned short* vp  = kp + (size_t)B_ * S_ * D_;
  unsigned short* wfp = vp + (size_t)B_ * S_ * D_;

  cvtw_kernel<<<384, 256, 0, stream>>>(Wq, Wk, Wv, wfp);
  qkv_kernel<<<256, 512, 0, stream>>>(x, wfp, bq, bk, bv, q, kp, vp);
  attn_kernel<<<256, 512, 0, stream>>>(q, kp, vp, out);
}